// Round 4
// baseline (384.772 us; speedup 1.0000x reference)
//
#include <hip/hip_runtime.h>
#include <hip/hip_bf16.h>

#define NPTS 500000
#define NGR  64

typedef __bf16 bf16x8 __attribute__((ext_vector_type(8)));
typedef float f32x4 __attribute__((ext_vector_type(4)));
typedef unsigned int u32x4 __attribute__((ext_vector_type(4)));

// ---- workspace layout (bytes), all 16B aligned ----
#define OFF_COMS   0        // f64[256] : per-graph {sx,sy,sz,count} raw sums
#define OFF_MIND   4096     // u64[64]  : packed (trunc-f64-d2 | id)
#define OFF_OUTACC 6144     // u32[8192]: order-preserving max accum
#define OFF_CBIAS  38912    // f32[8192]: per-graph GEMM1 bias row
#define OFF_W1PT   71680    // f32[512] : W1[128:131]^T padded [128][4]
#define OFF_W1AT   73728    // u16[8192]: bf16 W1[64:128]^T [n=128][k=64]
#define OFF_W2T    90112    // u16[16384]: bf16 W2^T [n=128][k=128]

// order-preserving float->u32 map (max over u32 == max over float)
__device__ __forceinline__ unsigned mapf(float f) {
    union { float f; unsigned u; } v; v.f = f;
    return ((int)v.u >= 0) ? (v.u | 0x80000000u) : ~v.u;
}

#define GLOAD_LDS16(g, l) __builtin_amdgcn_global_load_lds(                 \
    (__attribute__((address_space(1))) void*)(g),                           \
    (__attribute__((address_space(3))) void*)(l), 16, 0, 0)

__global__ void k_prep(const float* __restrict__ W1,
                       const float* __restrict__ W2,
                       unsigned short* __restrict__ W1aT,
                       unsigned short* __restrict__ W2T,
                       float* __restrict__ W1pT,
                       double* coms, unsigned long long* mind, unsigned* outacc) {
    int i = blockIdx.x * 256 + threadIdx.x;
    if (i < 8192) outacc[i] = 0u;
    if (i < 256) coms[i] = 0.0;
    if (i < 64) mind[i] = ~0ULL;
    if (i < 8192) {
        int n = i >> 6, k = i & 63;
        W1aT[i] = (unsigned short)(__builtin_bit_cast(unsigned, (float)(__bf16)W1[(64 + k) * 128 + n]) >> 16);
    } else if (i < 8192 + 16384) {
        int j = i - 8192; int n = j >> 7, k = j & 127;
        W2T[j] = (unsigned short)(__builtin_bit_cast(unsigned, (float)(__bf16)W2[k * 128 + n]) >> 16);
    } else if (i < 8192 + 16384 + 512) {
        int j = i - 24576; int n = j >> 2, q = j & 3;
        W1pT[j] = (q < 3) ? W1[(128 + q) * 128 + n] : 0.f;
    }
}

__global__ void k_com(const float* __restrict__ pos,
                      const int* __restrict__ batch, double* coms) {
    int i = blockIdx.x * 256 + threadIdx.x;
    int l = threadIdx.x & 63;
    bool valid = i < NPTS;
    int g = valid ? batch[i] : -1;
    double sx = valid ? (double)pos[i * 3 + 0] : 0.0;
    double sy = valid ? (double)pos[i * 3 + 1] : 0.0;
    double sz = valid ? (double)pos[i * 3 + 2] : 0.0;
    int gf = __shfl(g, 0), gl = __shfl(g, 63);
    bool uni = (gf == gl) && (gf >= 0);
    if (uni) {
        #pragma unroll
        for (int m = 1; m < 64; m <<= 1) {
            sx += __shfl_xor(sx, m);
            sy += __shfl_xor(sy, m);
            sz += __shfl_xor(sz, m);
        }
        if (l == 0) {
            atomicAdd(&coms[gf * 4 + 0], sx);
            atomicAdd(&coms[gf * 4 + 1], sy);
            atomicAdd(&coms[gf * 4 + 2], sz);
            atomicAdd(&coms[gf * 4 + 3], 64.0);
        }
    } else if (valid) {
        atomicAdd(&coms[g * 4 + 0], sx);
        atomicAdd(&coms[g * 4 + 1], sy);
        atomicAdd(&coms[g * 4 + 2], sz);
        atomicAdd(&coms[g * 4 + 3], 1.0);
    }
}

__global__ void k_min(const float* __restrict__ pos,
                      const int* __restrict__ batch,
                      const double* __restrict__ coms,
                      unsigned long long* mind) {
    int i = blockIdx.x * 256 + threadIdx.x;
    int l = threadIdx.x & 63;
    bool valid = i < NPTS;
    int g = valid ? batch[i] : -1;
    unsigned long long key = ~0ULL;
    if (valid) {
        double cnt = coms[g * 4 + 3];
        double rc = 1.0 / (cnt > 1.0 ? cnt : 1.0);
        double dx = (double)pos[i * 3 + 0] - coms[g * 4 + 0] * rc;
        double dy = (double)pos[i * 3 + 1] - coms[g * 4 + 1] * rc;
        double dz = (double)pos[i * 3 + 2] - coms[g * 4 + 2] * rc;
        double d2 = __builtin_fma(dx, dx, __builtin_fma(dy, dy, dz * dz));
        unsigned long long b = __builtin_bit_cast(unsigned long long, d2);
        key = (b & ~0xFFFFFULL) | (unsigned long long)i;
    }
    int gf = __shfl(g, 0), gl = __shfl(g, 63);
    bool uni = (gf == gl) && (gf >= 0);
    if (uni) {
        #pragma unroll
        for (int m = 1; m < 64; m <<= 1) {
            unsigned long long o = __shfl_xor(key, m);
            key = o < key ? o : key;
        }
        if (l == 0) atomicMin(&mind[gf], key);
    } else if (valid) {
        atomicMin(&mind[g], key);
    }
}

__global__ void k_fincb(const unsigned long long* __restrict__ mind,
                        const int* __restrict__ batch,
                        const float* __restrict__ pos,
                        const float* __restrict__ lfr,
                        const float* __restrict__ x,
                        const float* __restrict__ W1,
                        const float* __restrict__ b1,
                        float* __restrict__ cbias,
                        float* __restrict__ outf) {
    __shared__ float sposd[3];
    __shared__ int sid;
    int b = blockIdx.x, t = threadIdx.x;        // 64 x 128
    if (t == 0) {
        int id = (int)(mind[b] & 0xFFFFFULL);
        if (id > NPTS - 1) id = NPTS - 1;
        sid = id;
    }
    __syncthreads();
    int id = sid;
    if (t < 3) {
        float p = pos[id * 3 + t];
        sposd[t] = p;
        outf[8192 + b * 3 + t] = p;
    }
    if (t == 4) outf[8192 + 192 + b] = (float)batch[id];
    if (t < 9) outf[8192 + 256 + b * 9 + t] = lfr[id * 9 + t];
    __syncthreads();
    int c = t;
    float s = b1[c];
    for (int k = 0; k < 64; ++k) {
        float xd = x[id * 64 + k];
        s += xd * (W1[k * 128 + c] - W1[(64 + k) * 128 + c]);
    }
    s -= sposd[0] * W1[128 * 128 + c] + sposd[1] * W1[129 * 128 + c] + sposd[2] * W1[130 * 128 + c];
    cbias[b * 128 + c] = s;
}

__global__ __launch_bounds__(256) void k_main(
    const float* __restrict__ x,
    const float* __restrict__ pos,
    const int* __restrict__ batch,
    const unsigned short* __restrict__ W1aT,
    const unsigned short* __restrict__ W2T,
    const float* __restrict__ W1pT,
    const float* __restrict__ cbias,
    unsigned* __restrict__ outacc)
{
    // union: phase A = f32 x-tile [128][64] (32768 B); phase B = bf16 h [128][136] (34816 B)
    __shared__ alignas(16) unsigned char smem[128 * 136 * 2];

    const int tid = threadIdx.x;
    const int w = tid >> 6;
    const int lane = tid & 63;
    const int quad = lane >> 4;
    const int mr = lane & 15;
    const int row0 = blockIdx.x * 128;

    // ---- phase A: async-stage x tile (32 KB) into LDS; 2048 chunks of 16 B ----
    {
        const char* xbase = (const char*)x + (size_t)row0 * 256;
        #pragma unroll
        for (int i = 0; i < 8; ++i) {
            int c = i * 256 + tid;
            int cc = (row0 + (c >> 4) < NPTS) ? c : (c & 15);   // clamp OOB rows
            GLOAD_LDS16(xbase + cc * 16, (char*)smem + c * 16);
        }
    }

    // ---- prefetch per-row meta while staging is in flight ----
    int rowg[2][4]; bool rowv[2][4]; float rp[2][4][3];
    #pragma unroll
    for (int u = 0; u < 2; ++u)
        #pragma unroll
        for (int r = 0; r < 4; ++r) {
            int gr = row0 + 32 * w + 16 * u + quad * 4 + r;
            rowv[u][r] = (gr < NPTS);
            int grc = gr < NPTS ? gr : NPTS - 1;
            rowg[u][r] = batch[grc];
            rp[u][r][0] = pos[grc * 3 + 0];
            rp[u][r][1] = pos[grc * 3 + 1];
            rp[u][r][2] = pos[grc * 3 + 2];
        }

    __syncthreads();   // staging complete

    // ---- read A fragments from LDS (f32) and convert to bf16 ----
    bf16x8 afr[2][2];
    const float* xsf = (const float*)smem;
    #pragma unroll
    for (int u = 0; u < 2; ++u) {
        int lr = 32 * w + 16 * u + mr;
        #pragma unroll
        for (int h = 0; h < 2; ++h) {
            const f32x4* p = (const f32x4*)(xsf + lr * 64 + quad * 8 + h * 32);
            f32x4 va = p[0], vb = p[1];
            bf16x8 a;
            a[0] = (__bf16)va[0]; a[1] = (__bf16)va[1]; a[2] = (__bf16)va[2]; a[3] = (__bf16)va[3];
            a[4] = (__bf16)vb[0]; a[5] = (__bf16)vb[1]; a[6] = (__bf16)vb[2]; a[7] = (__bf16)vb[3];
            afr[u][h] = a;
        }
    }
    __syncthreads();   // x reads done; LDS reused for h

    // ---- GEMM1 ----
    f32x4 acc[2][8];
    #pragma unroll
    for (int u = 0; u < 2; ++u)
        #pragma unroll
        for (int t = 0; t < 8; ++t) acc[u][t] = (f32x4){0.f, 0.f, 0.f, 0.f};
    #pragma unroll
    for (int t = 0; t < 8; ++t) {
        const u32x4* pb = (const u32x4*)(W1aT + (t * 16 + mr) * 64 + quad * 8);
        bf16x8 bv0 = __builtin_bit_cast(bf16x8, pb[0]);
        bf16x8 bv1 = __builtin_bit_cast(bf16x8, pb[4]);
        #pragma unroll
        for (int u = 0; u < 2; ++u) {
            acc[u][t] = __builtin_amdgcn_mfma_f32_16x16x32_bf16(afr[u][0], bv0, acc[u][t], 0, 0, 0);
            acc[u][t] = __builtin_amdgcn_mfma_f32_16x16x32_bf16(afr[u][1], bv1, acc[u][t], 0, 0, 0);
        }
    }

    // ---- epilogue1: h = relu(acc + cbias[g] + pos.W1p) -> LDS bf16 ----
    f32x4 wpx[8];
    #pragma unroll
    for (int t = 0; t < 8; ++t) wpx[t] = *(const f32x4*)(W1pT + (t * 16 + mr) * 4);
    __bf16* hsb = (__bf16*)smem;
    #pragma unroll
    for (int u = 0; u < 2; ++u) {
        #pragma unroll
        for (int r = 0; r < 4; ++r) {
            int lrow = 32 * w + 16 * u + quad * 4 + r;
            int g = rowg[u][r];
            float p0 = rp[u][r][0], p1 = rp[u][r][1], p2 = rp[u][r][2];
            const float* crow = cbias + g * 128;
            #pragma unroll
            for (int t = 0; t < 8; ++t) {
                int col = t * 16 + mr;
                float v = acc[u][t][r] + crow[col]
                        + p0 * wpx[t][0] + p1 * wpx[t][1] + p2 * wpx[t][2];
                v = fmaxf(v, 0.f);
                hsb[lrow * 136 + col] = (__bf16)v;
            }
        }
    }
    __syncthreads();

    // ---- GEMM2 ----
    f32x4 acc2[2][8];
    #pragma unroll
    for (int u = 0; u < 2; ++u)
        #pragma unroll
        for (int t = 0; t < 8; ++t) acc2[u][t] = (f32x4){0.f, 0.f, 0.f, 0.f};
    const unsigned short* hs = (const unsigned short*)smem;
    #pragma unroll
    for (int kk = 0; kk < 4; ++kk) {
        bf16x8 a2[2];
        #pragma unroll
        for (int u = 0; u < 2; ++u) {
            const u32x4* ph = (const u32x4*)(hs + (32 * w + 16 * u + mr) * 136 + kk * 32 + quad * 8);
            a2[u] = __builtin_bit_cast(bf16x8, ph[0]);
        }
        #pragma unroll
        for (int t = 0; t < 8; ++t) {
            const u32x4* pb = (const u32x4*)(W2T + (t * 16 + mr) * 128 + kk * 32 + quad * 8);
            bf16x8 bv = __builtin_bit_cast(bf16x8, pb[0]);
            #pragma unroll
            for (int u = 0; u < 2; ++u)
                acc2[u][t] = __builtin_amdgcn_mfma_f32_16x16x32_bf16(a2[u], bv, acc2[u][t], 0, 0, 0);
        }
    }

    // ---- epilogue2: per-graph column max -> global atomicMax ----
    int gfirst = batch[row0];
    int rlast = row0 + 127; if (rlast > NPTS - 1) rlast = NPTS - 1;
    int glast = batch[rlast];
    for (int g = gfirst; g <= glast; ++g) {
        #pragma unroll
        for (int t = 0; t < 8; ++t) {
            float m = -INFINITY;
            #pragma unroll
            for (int u = 0; u < 2; ++u)
                #pragma unroll
                for (int r = 0; r < 4; ++r)
                    if (rowv[u][r] && rowg[u][r] == g) m = fmaxf(m, acc2[u][t][r]);
            m = fmaxf(m, __shfl_xor(m, 16));
            m = fmaxf(m, __shfl_xor(m, 32));
            unsigned mb = __builtin_bit_cast(unsigned, m);
            if (quad == 0 && mb != 0xFF800000u)
                atomicMax(&outacc[g * 128 + t * 16 + mr], mapf(m));
        }
    }
}

__global__ void k_out(const unsigned* __restrict__ outacc,
                      const float* __restrict__ b2v,
                      float* __restrict__ outf) {
    int i = blockIdx.x * 256 + threadIdx.x;   // 8192 threads
    unsigned key = outacc[i];
    float v;
    if (key == 0u) {
        v = -300.f;
    } else {
        unsigned bits = (key & 0x80000000u) ? (key & 0x7FFFFFFFu) : ~key;
        union { unsigned u; float f; } c; c.u = bits; v = c.f;
    }
    outf[i] = v + b2v[i & 127];
}

extern "C" void kernel_launch(void* const* d_in, const int* in_sizes, int n_in,
                              void* d_out, int out_size, void* d_ws, size_t ws_size,
                              hipStream_t stream) {
    const float* x   = (const float*)d_in[0];
    const float* pos = (const float*)d_in[1];
    const int*   bat = (const int*)d_in[2];
    const float* lfr = (const float*)d_in[3];
    const float* W1  = (const float*)d_in[4];
    const float* b1  = (const float*)d_in[5];
    const float* W2  = (const float*)d_in[6];
    const float* b2v = (const float*)d_in[7];
    float* outf = (float*)d_out;

    char* ws = (char*)d_ws;
    double*             coms   = (double*)(ws + OFF_COMS);
    unsigned long long* mind   = (unsigned long long*)(ws + OFF_MIND);
    unsigned*           outacc = (unsigned*)(ws + OFF_OUTACC);
    float*              cbias  = (float*)(ws + OFF_CBIAS);
    float*              W1pT   = (float*)(ws + OFF_W1PT);
    unsigned short*     W1aT   = (unsigned short*)(ws + OFF_W1AT);
    unsigned short*     W2T    = (unsigned short*)(ws + OFF_W2T);

    const int nblk = (NPTS + 255) / 256;      // 1954
    const int tblk = (NPTS + 127) / 128;      // 3907

    k_prep<<<98, 256, 0, stream>>>(W1, W2, W1aT, W2T, W1pT, coms, mind, outacc);
    k_com<<<nblk, 256, 0, stream>>>(pos, bat, coms);
    k_min<<<nblk, 256, 0, stream>>>(pos, bat, coms, mind);
    k_fincb<<<64, 128, 0, stream>>>(mind, bat, pos, lfr, x, W1, b1, cbias, outf);
    k_main<<<tblk, 256, 0, stream>>>(x, pos, bat, W1aT, W2T, W1pT, cbias, outacc);
    k_out<<<32, 256, 0, stream>>>(outacc, b2v, outf);
}

// Round 5
// 352.541 us; speedup vs baseline: 1.0914x; 1.0914x over previous
//
#include <hip/hip_runtime.h>
#include <hip/hip_bf16.h>

#define NPTS 500000
#define NGR  64
#define GRID_MAIN 512
#define NTILES ((NPTS + 127) / 128)   // 3907

typedef __bf16 bf16x8 __attribute__((ext_vector_type(8)));
typedef float f32x4 __attribute__((ext_vector_type(4)));
typedef unsigned int u32x4 __attribute__((ext_vector_type(4)));

// ---- workspace layout (bytes), all 16B aligned ----
#define OFF_COMS   0        // f64[256] : per-graph {sx,sy,sz,count} raw sums
#define OFF_MIND   4096     // u64[64]  : packed (trunc-f64-d2 | id)
#define OFF_OUTACC 6144     // u32[8192]: order-preserving max accum
#define OFF_CBIAS  38912    // f32[8192]: per-graph GEMM1 bias row
#define OFF_W1PT   71680    // f32[512] : W1[128:131]^T padded [128][4]
#define OFF_W1AT   73728    // u16[8192]: bf16 W1[64:128]^T [n=128][k=64]
#define OFF_W2T    90112    // u16[16384]: bf16 W2^T [n=128][k=128]

// order-preserving float->u32 map (max over u32 == max over float)
__device__ __forceinline__ unsigned mapf(float f) {
    union { float f; unsigned u; } v; v.f = f;
    return ((int)v.u >= 0) ? (v.u | 0x80000000u) : ~v.u;
}

#define GLOAD_LDS16(g, l) __builtin_amdgcn_global_load_lds(                 \
    (__attribute__((address_space(1))) void*)(g),                           \
    (__attribute__((address_space(3))) void*)(l), 16, 0, 0)

__global__ void k_prep(const float* __restrict__ W1,
                       const float* __restrict__ W2,
                       unsigned short* __restrict__ W1aT,
                       unsigned short* __restrict__ W2T,
                       float* __restrict__ W1pT,
                       double* coms, unsigned long long* mind, unsigned* outacc) {
    int i = blockIdx.x * 256 + threadIdx.x;
    if (i < 8192) outacc[i] = 0u;
    if (i < 256) coms[i] = 0.0;
    if (i < 64) mind[i] = ~0ULL;
    if (i < 8192) {
        int n = i >> 6, k = i & 63;
        W1aT[i] = (unsigned short)(__builtin_bit_cast(unsigned, (float)(__bf16)W1[(64 + k) * 128 + n]) >> 16);
    } else if (i < 8192 + 16384) {
        int j = i - 8192; int n = j >> 7, k = j & 127;
        W2T[j] = (unsigned short)(__builtin_bit_cast(unsigned, (float)(__bf16)W2[k * 128 + n]) >> 16);
    } else if (i < 8192 + 16384 + 512) {
        int j = i - 24576; int n = j >> 2, q = j & 3;
        W1pT[j] = (q < 3) ? W1[(128 + q) * 128 + n] : 0.f;
    }
}

__global__ void k_com(const float* __restrict__ pos,
                      const int* __restrict__ batch, double* coms) {
    int i = blockIdx.x * 256 + threadIdx.x;
    int l = threadIdx.x & 63;
    bool valid = i < NPTS;
    int g = valid ? batch[i] : -1;
    double sx = valid ? (double)pos[i * 3 + 0] : 0.0;
    double sy = valid ? (double)pos[i * 3 + 1] : 0.0;
    double sz = valid ? (double)pos[i * 3 + 2] : 0.0;
    int gf = __shfl(g, 0), gl = __shfl(g, 63);
    bool uni = (gf == gl) && (gf >= 0);
    if (uni) {
        #pragma unroll
        for (int m = 1; m < 64; m <<= 1) {
            sx += __shfl_xor(sx, m);
            sy += __shfl_xor(sy, m);
            sz += __shfl_xor(sz, m);
        }
        if (l == 0) {
            atomicAdd(&coms[gf * 4 + 0], sx);
            atomicAdd(&coms[gf * 4 + 1], sy);
            atomicAdd(&coms[gf * 4 + 2], sz);
            atomicAdd(&coms[gf * 4 + 3], 64.0);
        }
    } else if (valid) {
        atomicAdd(&coms[g * 4 + 0], sx);
        atomicAdd(&coms[g * 4 + 1], sy);
        atomicAdd(&coms[g * 4 + 2], sz);
        atomicAdd(&coms[g * 4 + 3], 1.0);
    }
}

__global__ void k_min(const float* __restrict__ pos,
                      const int* __restrict__ batch,
                      const double* __restrict__ coms,
                      unsigned long long* mind) {
    int i = blockIdx.x * 256 + threadIdx.x;
    int l = threadIdx.x & 63;
    bool valid = i < NPTS;
    int g = valid ? batch[i] : -1;
    unsigned long long key = ~0ULL;
    if (valid) {
        double cnt = coms[g * 4 + 3];
        double rc = 1.0 / (cnt > 1.0 ? cnt : 1.0);
        double dx = (double)pos[i * 3 + 0] - coms[g * 4 + 0] * rc;
        double dy = (double)pos[i * 3 + 1] - coms[g * 4 + 1] * rc;
        double dz = (double)pos[i * 3 + 2] - coms[g * 4 + 2] * rc;
        double d2 = __builtin_fma(dx, dx, __builtin_fma(dy, dy, dz * dz));
        unsigned long long b = __builtin_bit_cast(unsigned long long, d2);
        key = (b & ~0xFFFFFULL) | (unsigned long long)i;
    }
    int gf = __shfl(g, 0), gl = __shfl(g, 63);
    bool uni = (gf == gl) && (gf >= 0);
    if (uni) {
        #pragma unroll
        for (int m = 1; m < 64; m <<= 1) {
            unsigned long long o = __shfl_xor(key, m);
            key = o < key ? o : key;
        }
        if (l == 0) atomicMin(&mind[gf], key);
    } else if (valid) {
        atomicMin(&mind[g], key);
    }
}

__global__ void k_fincb(const unsigned long long* __restrict__ mind,
                        const int* __restrict__ batch,
                        const float* __restrict__ pos,
                        const float* __restrict__ lfr,
                        const float* __restrict__ x,
                        const float* __restrict__ W1,
                        const float* __restrict__ b1,
                        float* __restrict__ cbias,
                        float* __restrict__ outf) {
    __shared__ float sposd[3];
    __shared__ int sid;
    int b = blockIdx.x, t = threadIdx.x;        // 64 x 128
    if (t == 0) {
        int id = (int)(mind[b] & 0xFFFFFULL);
        if (id > NPTS - 1) id = NPTS - 1;
        sid = id;
    }
    __syncthreads();
    int id = sid;
    if (t < 3) {
        float p = pos[id * 3 + t];
        sposd[t] = p;
        outf[8192 + b * 3 + t] = p;
    }
    if (t == 4) outf[8192 + 192 + b] = (float)batch[id];
    if (t < 9) outf[8192 + 256 + b * 9 + t] = lfr[id * 9 + t];
    __syncthreads();
    int c = t;
    float s = b1[c];
    for (int k = 0; k < 64; ++k) {
        float xd = x[id * 64 + k];
        s += xd * (W1[k * 128 + c] - W1[(64 + k) * 128 + c]);
    }
    s -= sposd[0] * W1[128 * 128 + c] + sposd[1] * W1[129 * 128 + c] + sposd[2] * W1[130 * 128 + c];
    cbias[b * 128 + c] = s;
}

__global__ __launch_bounds__(256, 4) void k_main(
    const float* __restrict__ x,
    const float* __restrict__ pos,
    const int* __restrict__ batch,
    const unsigned short* __restrict__ W1aT,
    const unsigned short* __restrict__ W2T,
    const float* __restrict__ W1pT,
    const float* __restrict__ cbias,
    unsigned* __restrict__ outacc)
{
    // double buffer: phase A = f32 x-tile (XOR-swizzled 16B chunks, 32768 B used);
    // phase B (same buffer) = bf16 h [128][136] (34816 B)
    __shared__ alignas(16) unsigned char smem[2][34816];

    const int tid = threadIdx.x;
    const int w = tid >> 6;
    const int lane = tid & 63;
    const int quad = lane >> 4;
    const int mr = lane & 15;

    // stage tile tt into buffer b: LDS chunk c holds global (row r=c>>4, colgroup (c&15)^(r&15))
    auto stage = [&](int tt, int b) {
        const char* xb = (const char*)x + (size_t)tt * 32768;   // 128 rows * 256 B
        #pragma unroll
        for (int i = 0; i < 8; ++i) {
            int c = i * 256 + tid;
            int r = c >> 4;
            int cg = (c & 15) ^ (r & 15);
            int src = (tt * 128 + r < NPTS) ? (r * 16 + cg) : (c & 15);  // OOB -> tile row 0
            GLOAD_LDS16(xb + src * 16, (char*)&smem[b][0] + c * 16);
        }
    };

    // tile-invariant: B-ext fragments for the pos.W1p K-extension MFMA
    // B[n][k] layout: lane holds n = t*16+mr, k = quad*8+j. Nonzero only quad==0, j<3.
    bf16x8 bfrE[8];
    #pragma unroll
    for (int t = 0; t < 8; ++t) {
        f32x4 wp = *(const f32x4*)(W1pT + (t * 16 + mr) * 4);
        bf16x8 e = (bf16x8){0, 0, 0, 0, 0, 0, 0, 0};
        if (quad == 0) { e[0] = (__bf16)wp[0]; e[1] = (__bf16)wp[1]; e[2] = (__bf16)wp[2]; }
        bfrE[t] = e;
    }

    int pb = 0;
    int t0 = blockIdx.x;
    if (t0 < NTILES) stage(t0, 0);

    for (int t = t0; t < NTILES; t += GRID_MAIN, pb ^= 1) {
        const int row0 = t * 128;

        // ---- per-tile meta (issued before barrier; completes during drain) ----
        int rowg[2][4]; bool rowv[2][4];
        #pragma unroll
        for (int u = 0; u < 2; ++u)
            #pragma unroll
            for (int r = 0; r < 4; ++r) {
                int gr = row0 + 32 * w + 16 * u + quad * 4 + r;
                rowv[u][r] = (gr < NPTS);
                rowg[u][r] = batch[gr < NPTS ? gr : NPTS - 1];
            }
        int gfirst = batch[row0];
        int rl = row0 + 127; if (rl > NPTS - 1) rl = NPTS - 1;
        int glast = batch[rl];
        float cb0[8];
        #pragma unroll
        for (int tt = 0; tt < 8; ++tt) cb0[tt] = cbias[gfirst * 128 + tt * 16 + mr];
        // A-ext: this lane's A-row pos (rows 32w+16u+mr), k<3 lanes only (quad==0)
        float pE[2][3];
        #pragma unroll
        for (int u = 0; u < 2; ++u) {
            int gr2 = row0 + 32 * w + 16 * u + mr;
            int gc2 = gr2 < NPTS ? gr2 : NPTS - 1;
            pE[u][0] = pos[gc2 * 3 + 0];
            pE[u][1] = pos[gc2 * 3 + 1];
            pE[u][2] = pos[gc2 * 3 + 2];
        }

        __syncthreads();   // drains dma(t) for all waves; buf pb ready; buf pb^1 fully consumed

        int tn = t + GRID_MAIN;
        if (tn < NTILES) stage(tn, pb ^ 1);   // in flight across ALL compute below

        // ---- A fragments from swizzled LDS (f32 -> bf16) ----
        const float* xsf = (const float*)&smem[pb][0];
        bf16x8 afr[2][2];
        #pragma unroll
        for (int u = 0; u < 2; ++u) {
            int lr = 32 * w + 16 * u + mr;
            int base = lr * 16;
            #pragma unroll
            for (int h = 0; h < 2; ++h) {
                int cgA = 2 * quad + 8 * h;
                f32x4 va = *(const f32x4*)(xsf + (base + (cgA ^ mr)) * 4);
                f32x4 vb = *(const f32x4*)(xsf + (base + ((cgA + 1) ^ mr)) * 4);
                bf16x8 a;
                a[0] = (__bf16)va[0]; a[1] = (__bf16)va[1]; a[2] = (__bf16)va[2]; a[3] = (__bf16)va[3];
                a[4] = (__bf16)vb[0]; a[5] = (__bf16)vb[1]; a[6] = (__bf16)vb[2]; a[7] = (__bf16)vb[3];
                afr[u][h] = a;
            }
        }

        // ---- GEMM1 + pos.W1p K-extension ----
        f32x4 acc[2][8];
        #pragma unroll
        for (int u = 0; u < 2; ++u)
            #pragma unroll
            for (int tt = 0; tt < 8; ++tt) acc[u][tt] = (f32x4){0.f, 0.f, 0.f, 0.f};
        #pragma unroll
        for (int tt = 0; tt < 8; ++tt) {
            const u32x4* pbv = (const u32x4*)(W1aT + (tt * 16 + mr) * 64 + quad * 8);
            bf16x8 bv0 = __builtin_bit_cast(bf16x8, pbv[0]);
            bf16x8 bv1 = __builtin_bit_cast(bf16x8, pbv[4]);
            #pragma unroll
            for (int u = 0; u < 2; ++u) {
                acc[u][tt] = __builtin_amdgcn_mfma_f32_16x16x32_bf16(afr[u][0], bv0, acc[u][tt], 0, 0, 0);
                acc[u][tt] = __builtin_amdgcn_mfma_f32_16x16x32_bf16(afr[u][1], bv1, acc[u][tt], 0, 0, 0);
            }
        }
        bf16x8 aE[2];
        #pragma unroll
        for (int u = 0; u < 2; ++u) {
            bf16x8 a = (bf16x8){0, 0, 0, 0, 0, 0, 0, 0};
            if (quad == 0) { a[0] = (__bf16)pE[u][0]; a[1] = (__bf16)pE[u][1]; a[2] = (__bf16)pE[u][2]; }
            aE[u] = a;
        }
        #pragma unroll
        for (int tt = 0; tt < 8; ++tt)
            #pragma unroll
            for (int u = 0; u < 2; ++u)
                acc[u][tt] = __builtin_amdgcn_mfma_f32_16x16x32_bf16(aE[u], bfrE[tt], acc[u][tt], 0, 0, 0);

        // ---- epilogue1: h = relu(acc + cbias[g]) -> LDS bf16 [128][136] (wave-local rows) ----
        __bf16* hsb = (__bf16*)&smem[pb][0];
        #pragma unroll
        for (int u = 0; u < 2; ++u) {
            #pragma unroll
            for (int r = 0; r < 4; ++r) {
                int lrow = 32 * w + 16 * u + quad * 4 + r;
                int g = rowg[u][r];
                bool odd = (g != gfirst);
                #pragma unroll
                for (int tt = 0; tt < 8; ++tt) {
                    float cbv = cb0[tt];
                    if (odd) cbv = cbias[g * 128 + tt * 16 + mr];
                    float v = fmaxf(acc[u][tt][r] + cbv, 0.f);
                    hsb[lrow * 136 + tt * 16 + mr] = (__bf16)v;
                }
            }
        }
        // no barrier: GEMM2 reads only this wave's own 32-row stripe

        // ---- GEMM2 ----
        f32x4 acc2[2][8];
        #pragma unroll
        for (int u = 0; u < 2; ++u)
            #pragma unroll
            for (int tt = 0; tt < 8; ++tt) acc2[u][tt] = (f32x4){0.f, 0.f, 0.f, 0.f};
        const unsigned short* hs = (const unsigned short*)&smem[pb][0];
        #pragma unroll
        for (int kk = 0; kk < 4; ++kk) {
            bf16x8 a2[2];
            #pragma unroll
            for (int u = 0; u < 2; ++u) {
                const u32x4* ph = (const u32x4*)(hs + (32 * w + 16 * u + mr) * 136 + kk * 32 + quad * 8);
                a2[u] = __builtin_bit_cast(bf16x8, ph[0]);
            }
            #pragma unroll
            for (int tt = 0; tt < 8; ++tt) {
                const u32x4* pbv = (const u32x4*)(W2T + (tt * 16 + mr) * 128 + kk * 32 + quad * 8);
                bf16x8 bv = __builtin_bit_cast(bf16x8, pbv[0]);
                #pragma unroll
                for (int u = 0; u < 2; ++u)
                    acc2[u][tt] = __builtin_amdgcn_mfma_f32_16x16x32_bf16(a2[u], bv, acc2[u][tt], 0, 0, 0);
            }
        }

        // ---- epilogue2: per-graph column max -> global atomicMax ----
        for (int g = gfirst; g <= glast; ++g) {
            #pragma unroll
            for (int tt = 0; tt < 8; ++tt) {
                float m = -INFINITY;
                #pragma unroll
                for (int u = 0; u < 2; ++u)
                    #pragma unroll
                    for (int r = 0; r < 4; ++r)
                        if (rowv[u][r] && rowg[u][r] == g) m = fmaxf(m, acc2[u][tt][r]);
                m = fmaxf(m, __shfl_xor(m, 16));
                m = fmaxf(m, __shfl_xor(m, 32));
                unsigned mb = __builtin_bit_cast(unsigned, m);
                if (quad == 0 && mb != 0xFF800000u)
                    atomicMax(&outacc[g * 128 + tt * 16 + mr], mapf(m));
            }
        }
    }
}

__global__ void k_out(const unsigned* __restrict__ outacc,
                      const float* __restrict__ b2v,
                      float* __restrict__ outf) {
    int i = blockIdx.x * 256 + threadIdx.x;   // 8192 threads
    unsigned key = outacc[i];
    float v;
    if (key == 0u) {
        v = -300.f;   // diagnostic: never updated
    } else {
        unsigned bits = (key & 0x80000000u) ? (key & 0x7FFFFFFFu) : ~key;
        union { unsigned u; float f; } c; c.u = bits; v = c.f;
    }
    outf[i] = v + b2v[i & 127];
}

extern "C" void kernel_launch(void* const* d_in, const int* in_sizes, int n_in,
                              void* d_out, int out_size, void* d_ws, size_t ws_size,
                              hipStream_t stream) {
    const float* x   = (const float*)d_in[0];
    const float* pos = (const float*)d_in[1];
    const int*   bat = (const int*)d_in[2];
    const float* lfr = (const float*)d_in[3];
    const float* W1  = (const float*)d_in[4];
    const float* b1  = (const float*)d_in[5];
    const float* W2  = (const float*)d_in[6];
    const float* b2v = (const float*)d_in[7];
    float* outf = (float*)d_out;

    char* ws = (char*)d_ws;
    double*             coms   = (double*)(ws + OFF_COMS);
    unsigned long long* mind   = (unsigned long long*)(ws + OFF_MIND);
    unsigned*           outacc = (unsigned*)(ws + OFF_OUTACC);
    float*              cbias  = (float*)(ws + OFF_CBIAS);
    float*              W1pT   = (float*)(ws + OFF_W1PT);
    unsigned short*     W1aT   = (unsigned short*)(ws + OFF_W1AT);
    unsigned short*     W2T    = (unsigned short*)(ws + OFF_W2T);

    const int nblk = (NPTS + 255) / 256;      // 1954

    k_prep<<<98, 256, 0, stream>>>(W1, W2, W1aT, W2T, W1pT, coms, mind, outacc);
    k_com<<<nblk, 256, 0, stream>>>(pos, bat, coms);
    k_min<<<nblk, 256, 0, stream>>>(pos, bat, coms, mind);
    k_fincb<<<64, 128, 0, stream>>>(mind, bat, pos, lfr, x, W1, b1, cbias, outf);
    k_main<<<GRID_MAIN, 256, 0, stream>>>(x, pos, bat, W1aT, W2T, W1pT, cbias, outacc);
    k_out<<<32, 256, 0, stream>>>(outacc, b2v, outf);
}